// Round 1
// baseline (336.176 us; speedup 1.0000x reference)
//
#include <hip/hip_runtime.h>
#include <stdint.h>

// Sizes fixed by the problem
#define BSZ 4
#define NSEQ 512
#define DMOD 1024
#define NH 16
#define HD 64

typedef __attribute__((ext_vector_type(8))) short bf16x8;
typedef __attribute__((ext_vector_type(4))) float f32x4;

__device__ __forceinline__ unsigned short f2bf(float f) {
    union { float f; uint32_t u; } v; v.f = f;
    uint32_t u = v.u;
    u += 0x7FFFu + ((u >> 16) & 1u);   // RNE
    return (unsigned short)(u >> 16);
}
__device__ __forceinline__ float bf2f(unsigned short b) {
    union { float f; uint32_t u; } v; v.u = ((uint32_t)b) << 16;
    return v.f;
}

// ---------------- stage 1: conversions ----------------
__global__ void k_cvt(const float* __restrict__ src, unsigned short* __restrict__ dst, int n) {
    int i = blockIdx.x * blockDim.x + threadIdx.x;
    if (i < n) dst[i] = f2bf(src[i]);
}

// transpose-convert weight: src[e][c] fp32 (1024x1024) -> dst[c][e] bf16
__global__ void k_cvt_wt(const float* __restrict__ src, unsigned short* __restrict__ dst) {
    __shared__ float t[32][33];
    int be = blockIdx.x * 32;   // e tile base
    int bc = blockIdx.y * 32;   // c tile base
    int tx = threadIdx.x & 31, ty = threadIdx.x >> 5;  // 32 x 8
    #pragma unroll
    for (int yy = 0; yy < 32; yy += 8)
        t[ty + yy][tx] = src[(size_t)(be + ty + yy) * DMOD + bc + tx];
    __syncthreads();
    #pragma unroll
    for (int yy = 0; yy < 32; yy += 8)
        dst[(size_t)(bc + ty + yy) * DMOD + be + tx] = f2bf(t[tx][ty + yy]);
}

// ---------------- stage 2: wv2t[h][e] = sum_d wv[e][h*64+d]*wo[h*64+d], bv2[h] ----------------
__global__ void k_wv2(const float* __restrict__ wv, const float* __restrict__ bv,
                      const float* __restrict__ wo,
                      float* __restrict__ wv2t, float* __restrict__ bv2) {
    int grp = threadIdx.x >> 6, l = threadIdx.x & 63;
    int e = blockIdx.x * 4 + grp;
    float out = 0.f;
    #pragma unroll
    for (int it = 0; it < 16; ++it) {      // column c = it*64 + l  ->  h = it, d = l
        float v = wv[(size_t)e * DMOD + it * 64 + l] * wo[it * 64 + l];
        #pragma unroll
        for (int off = 1; off < 64; off <<= 1) v += __shfl_xor(v, off, 64);
        if (l == it) out = v;
    }
    if (l < 16) wv2t[l * DMOD + e] = out;
    if (blockIdx.x == 0 && grp == 0) {
        float ob = 0.f;
        #pragma unroll
        for (int it = 0; it < 16; ++it) {
            float v = bv[it * 64 + l] * wo[it * 64 + l];
            #pragma unroll
            for (int off = 1; off < 64; off <<= 1) v += __shfl_xor(v, off, 64);
            if (l == it) ob = v;
        }
        if (l < 16) bv2[l] = ob;
    }
}

// ---------------- stage 2b: u[b][h][j] = x[b,j,:] @ wv2t[h,:] + bv2[h]  (fp32) ----------------
__global__ void k_u(const float* __restrict__ x, const float* __restrict__ wv2t,
                    const float* __restrict__ bv2, float* __restrict__ u) {
    int wave = blockIdx.x * 4 + (threadIdx.x >> 6);  // 2048 waves: one per (b,j)
    int l = threadIdx.x & 63;
    int b = wave >> 9, j = wave & 511;
    const float* xr = x + (size_t)(b * NSEQ + j) * DMOD;
    float p[16];
    #pragma unroll
    for (int h = 0; h < 16; ++h) p[h] = 0.f;
    for (int it = 0; it < 16; ++it) {
        int e = l + it * 64;
        float xv = xr[e];
        #pragma unroll
        for (int h = 0; h < 16; ++h) p[h] += xv * wv2t[h * DMOD + e];
    }
    #pragma unroll
    for (int h = 0; h < 16; ++h) {
        #pragma unroll
        for (int off = 1; off < 64; off <<= 1) p[h] += __shfl_xor(p[h], off, 64);
    }
    float out = 0.f;
    #pragma unroll
    for (int h = 0; h < 16; ++h) if (l == h) out = p[h] + bv2[h];
    if (l < 16) u[(b * 16 + l) * NSEQ + j] = out;
}

// ---------------- stage 3: projection GEMM (bf16 MFMA) ----------------
// C[m][n] = X[m][:] @ Wt[n][:]^T + bias[n]; out stored transposed as [b,h,i,d] bf16.
// Block: 256 thr = 4 waves; block tile 64(m) x 64(n); wave: 16(m) x 64(n).
__global__ __launch_bounds__(256) void k_gemm(
        const unsigned short* __restrict__ X,    // 2048 x 1024 bf16 row-major
        const unsigned short* __restrict__ Wt,   // [n][k] 1024 x 1024 bf16
        const float* __restrict__ bias,          // [1024]
        unsigned short* __restrict__ outT) {     // [b*16+h][i][d] bf16
    int w = threadIdx.x >> 6, lane = threadIdx.x & 63;
    int quad = lane >> 4, col = lane & 15;
    int m0 = blockIdx.x * 64 + w * 16;
    int n0 = blockIdx.y * 64;
    f32x4 acc[4];
    #pragma unroll
    for (int nt = 0; nt < 4; ++nt) acc[nt] = (f32x4){0.f, 0.f, 0.f, 0.f};
    const unsigned short* arow = X + (size_t)(m0 + col) * DMOD + quad * 8;
    for (int k0 = 0; k0 < DMOD; k0 += 32) {
        bf16x8 a = *(const bf16x8*)(arow + k0);
        #pragma unroll
        for (int nt = 0; nt < 4; ++nt) {
            bf16x8 bf = *(const bf16x8*)(Wt + (size_t)(n0 + nt * 16 + col) * DMOD + k0 + quad * 8);
            acc[nt] = __builtin_amdgcn_mfma_f32_16x16x32_bf16(a, bf, acc[nt], 0, 0, 0);
        }
    }
    #pragma unroll
    for (int nt = 0; nt < 4; ++nt) {
        int n = n0 + nt * 16 + col;       // D-output col: lane&15 = N index
        int h = n >> 6, d = n & 63;
        float bvv = bias[n];
        #pragma unroll
        for (int r = 0; r < 4; ++r) {
            int mg = m0 + quad * 4 + r;   // D-output row: quad*4+reg = M index
            int b = mg >> 9, i = mg & 511;
            outT[(size_t)((b * 16 + h) * NSEQ + i) * HD + d] = f2bf(acc[r == 0 ? nt : nt][r] + bvv);
        }
    }
}

// ---------------- stage 4: logits + bias + mask + fixed-shift exp ----------------
// Per wave: 16 i-rows x all 512 j. e = exp(qk/8 + bias - 30) (0 if masked), bf16 out.
// sinv[b,h,i] = 1/sum_j e.
__global__ __launch_bounds__(256) void k_logits(
        const unsigned short* __restrict__ qT, const unsigned short* __restrict__ kT,
        const float* __restrict__ bias, const int* __restrict__ mask,
        unsigned short* __restrict__ eW, float* __restrict__ sinv) {
    int w = threadIdx.x >> 6, lane = threadIdx.x & 63;
    int quad = lane >> 4, col = lane & 15;
    int b = blockIdx.z, h = blockIdx.y;
    int i0 = blockIdx.x * 64 + w * 16;
    int bh = b * 16 + h;
    const unsigned short* qbase = qT + (size_t)(bh * NSEQ + i0) * HD + (size_t)col * HD + quad * 8;
    bf16x8 a0 = *(const bf16x8*)(qbase);
    bf16x8 a1 = *(const bf16x8*)(qbase + 32);
    float sp[4] = {0.f, 0.f, 0.f, 0.f};
    for (int jt = 0; jt < 32; ++jt) {
        int j0 = jt * 16;
        const unsigned short* kbase = kT + (size_t)(bh * NSEQ + j0) * HD + (size_t)col * HD + quad * 8;
        bf16x8 b0 = *(const bf16x8*)(kbase);
        bf16x8 b1 = *(const bf16x8*)(kbase + 32);
        f32x4 acc = (f32x4){0.f, 0.f, 0.f, 0.f};
        acc = __builtin_amdgcn_mfma_f32_16x16x32_bf16(a0, b0, acc, 0, 0, 0);
        acc = __builtin_amdgcn_mfma_f32_16x16x32_bf16(a1, b1, acc, 0, 0, 0);
        int j = j0 + col;
        #pragma unroll
        for (int r = 0; r < 4; ++r) {
            int i = i0 + quad * 4 + r;
            float lg = acc[r] * 0.125f + bias[(size_t)(bh * NSEQ + i) * NSEQ + j];
            int mk = mask[(size_t)(b * NSEQ + i) * NSEQ + j];
            float e = (mk == 0) ? 0.f : __expf(lg - 30.f);
            sp[r] += e;
            eW[(size_t)(bh * NSEQ + i) * NSEQ + j] = f2bf(e);
        }
    }
    #pragma unroll
    for (int r = 0; r < 4; ++r) {
        #pragma unroll
        for (int off = 1; off < 16; off <<= 1) sp[r] += __shfl_xor(sp[r], off, 64);
    }
    if (col == 0) {
        #pragma unroll
        for (int r = 0; r < 4; ++r) {
            float s = sp[r];
            sinv[bh * NSEQ + i0 + quad * 4 + r] = (s > 0.f) ? 1.f / s : 0.f;
        }
    }
}

// ---------------- stage 5: combine: force[b,i,c] = bo + sum_j r * sum_h e*sinv*u ----------------
__global__ __launch_bounds__(256) void k_combine(
        const unsigned short* __restrict__ eW, const float* __restrict__ sinv,
        const float* __restrict__ u, const float* __restrict__ r,
        const float* __restrict__ bo, float* __restrict__ out) {
    int i = blockIdx.x, b = blockIdx.y;
    int tid = threadIdx.x;
    __shared__ float su[16];
    __shared__ float red[3][4];
    if (tid < 16) su[tid] = sinv[(b * 16 + tid) * NSEQ + i];
    __syncthreads();
    float a0 = 0.f, a1 = 0.f, a2 = 0.f;
    #pragma unroll
    for (int jj = 0; jj < 2; ++jj) {
        int j = tid + jj * 256;
        float s = 0.f;
        #pragma unroll
        for (int h = 0; h < 16; ++h) {
            float e = bf2f(eW[(size_t)((b * 16 + h) * NSEQ + i) * NSEQ + j]);
            s += e * su[h] * u[(b * 16 + h) * NSEQ + j];
        }
        a0 += r[((size_t)(b * 3 + 0) * NSEQ + i) * NSEQ + j] * s;
        a1 += r[((size_t)(b * 3 + 1) * NSEQ + i) * NSEQ + j] * s;
        a2 += r[((size_t)(b * 3 + 2) * NSEQ + i) * NSEQ + j] * s;
    }
    #pragma unroll
    for (int off = 1; off < 64; off <<= 1) {
        a0 += __shfl_xor(a0, off, 64);
        a1 += __shfl_xor(a1, off, 64);
        a2 += __shfl_xor(a2, off, 64);
    }
    int w = tid >> 6, lane = tid & 63;
    if (lane == 0) { red[0][w] = a0; red[1][w] = a1; red[2][w] = a2; }
    __syncthreads();
    if (tid == 0) {
        float bov = bo[0];
        #pragma unroll
        for (int c = 0; c < 3; ++c) {
            out[(size_t)(b * NSEQ + i) * 3 + c] =
                red[c][0] + red[c][1] + red[c][2] + red[c][3] + bov;
        }
    }
}

extern "C" void kernel_launch(void* const* d_in, const int* in_sizes, int n_in,
                              void* d_out, int out_size, void* d_ws, size_t ws_size,
                              hipStream_t stream) {
    const float* x    = (const float*)d_in[0];
    const float* rr   = (const float*)d_in[1];
    const float* bias = (const float*)d_in[2];
    const int*   mask = (const int*)d_in[3];
    const float* wq   = (const float*)d_in[4];
    const float* bq   = (const float*)d_in[5];
    const float* wk   = (const float*)d_in[6];
    const float* bk   = (const float*)d_in[7];
    const float* wv   = (const float*)d_in[8];
    const float* bv   = (const float*)d_in[9];
    const float* wo   = (const float*)d_in[10];
    const float* bo   = (const float*)d_in[11];
    float* out = (float*)d_out;

    char* ws = (char*)d_ws;
    // workspace layout (bytes)
    unsigned short* xb   = (unsigned short*)(ws + 0);          //  2048*1024 bf16 = 4 MiB
    unsigned short* wqt  = (unsigned short*)(ws + 4194304);    //  1024*1024 bf16 = 2 MiB
    unsigned short* wkt  = (unsigned short*)(ws + 6291456);    //  2 MiB
    float*          wv2t = (float*)(ws + 8388608);             //  16*1024 f32 = 64 KiB
    float*          bv2  = (float*)(ws + 8454144);             //  16 f32 (+pad)
    float*          u    = (float*)(ws + 8454400);             //  4*16*512 f32 = 128 KiB
    unsigned short* qT   = (unsigned short*)(ws + 8585472);    //  [b,h,i,d] bf16 = 4 MiB
    unsigned short* kT   = (unsigned short*)(ws + 12779776);   //  4 MiB
    unsigned short* eW   = (unsigned short*)(ws + 16974080);   //  [b,h,i,j] bf16 = 32 MiB
    float*          siv  = (float*)(ws + 50528512);            //  [b,h,i] f32 = 128 KiB
    // total 50,659,584 bytes

    k_cvt<<<8192, 256, 0, stream>>>(x, xb, BSZ * NSEQ * DMOD);
    k_cvt_wt<<<dim3(32, 32), 256, 0, stream>>>(wq, wqt);
    k_cvt_wt<<<dim3(32, 32), 256, 0, stream>>>(wk, wkt);
    k_wv2<<<256, 256, 0, stream>>>(wv, bv, wo, wv2t, bv2);
    k_u<<<512, 256, 0, stream>>>(x, wv2t, bv2, u);
    k_gemm<<<dim3(32, 16), 256, 0, stream>>>(xb, wqt, bq, qT);
    k_gemm<<<dim3(32, 16), 256, 0, stream>>>(xb, wkt, bk, kT);
    k_logits<<<dim3(8, 16, 4), 256, 0, stream>>>(qT, kT, bias, mask, eW, siv);
    k_combine<<<dim3(512, 4), 256, 0, stream>>>(eW, siv, u, rr, bo, out);
}

// Round 2
// 307.995 us; speedup vs baseline: 1.0915x; 1.0915x over previous
//
#include <hip/hip_runtime.h>
#include <stdint.h>

// Sizes fixed by the problem
#define BSZ 4
#define NSEQ 512
#define DMOD 1024
#define NH 16
#define HD 64

typedef __attribute__((ext_vector_type(8))) short bf16x8;
typedef __attribute__((ext_vector_type(4))) float f32x4;

__device__ __forceinline__ unsigned short f2bf(float f) {
    union { float f; uint32_t u; } v; v.f = f;
    uint32_t u = v.u;
    u += 0x7FFFu + ((u >> 16) & 1u);   // RNE
    return (unsigned short)(u >> 16);
}
__device__ __forceinline__ float bf2f(unsigned short b) {
    union { float f; uint32_t u; } v; v.u = ((uint32_t)b) << 16;
    return v.f;
}

// ---------------- stage 1: conversions ----------------
__global__ void k_cvt(const float* __restrict__ src, unsigned short* __restrict__ dst, int n) {
    int i = blockIdx.x * blockDim.x + threadIdx.x;
    if (i < n) dst[i] = f2bf(src[i]);
}

// transpose-convert weight: src[e][c] fp32 (1024x1024) -> dst[c][e] bf16; z selects wq/wk
__global__ void k_cvt_wt(const float* __restrict__ wq, const float* __restrict__ wk,
                         unsigned short* __restrict__ wqt, unsigned short* __restrict__ wkt) {
    const float* src = blockIdx.z ? wk : wq;
    unsigned short* dst = blockIdx.z ? wkt : wqt;
    __shared__ float t[32][33];
    int be = blockIdx.x * 32;   // e tile base
    int bc = blockIdx.y * 32;   // c tile base
    int tx = threadIdx.x & 31, ty = threadIdx.x >> 5;  // 32 x 8
    #pragma unroll
    for (int yy = 0; yy < 32; yy += 8)
        t[ty + yy][tx] = src[(size_t)(be + ty + yy) * DMOD + bc + tx];
    __syncthreads();
    #pragma unroll
    for (int yy = 0; yy < 32; yy += 8)
        dst[(size_t)(bc + ty + yy) * DMOD + be + tx] = f2bf(t[tx][ty + yy]);
}

// ---------------- stage 2: wv2t[h][e] = sum_d wv[e][h*64+d]*wo[h*64+d], bv2[h] ----------------
__global__ void k_wv2(const float* __restrict__ wv, const float* __restrict__ bv,
                      const float* __restrict__ wo,
                      float* __restrict__ wv2t, float* __restrict__ bv2) {
    int grp = threadIdx.x >> 6, l = threadIdx.x & 63;
    int e = blockIdx.x * 4 + grp;
    float out = 0.f;
    #pragma unroll
    for (int it = 0; it < 16; ++it) {      // column c = it*64 + l  ->  h = it, d = l
        float v = wv[(size_t)e * DMOD + it * 64 + l] * wo[it * 64 + l];
        #pragma unroll
        for (int off = 1; off < 64; off <<= 1) v += __shfl_xor(v, off, 64);
        if (l == it) out = v;
    }
    if (l < 16) wv2t[l * DMOD + e] = out;
    if (blockIdx.x == 0 && grp == 0) {
        float ob = 0.f;
        #pragma unroll
        for (int it = 0; it < 16; ++it) {
            float v = bv[it * 64 + l] * wo[it * 64 + l];
            #pragma unroll
            for (int off = 1; off < 64; off <<= 1) v += __shfl_xor(v, off, 64);
            if (l == it) ob = v;
        }
        if (l < 16) bv2[l] = ob;
    }
}

// ---------------- stage 2b: u[b][h][j] = x[b,j,:] @ wv2t[h,:] + bv2[h]  (fp32) ----------------
__global__ void k_u(const float* __restrict__ x, const float* __restrict__ wv2t,
                    const float* __restrict__ bv2, float* __restrict__ u) {
    int wave = blockIdx.x * 4 + (threadIdx.x >> 6);  // 2048 waves: one per (b,j)
    int l = threadIdx.x & 63;
    int b = wave >> 9, j = wave & 511;
    const float* xr = x + (size_t)(b * NSEQ + j) * DMOD;
    float p[16];
    #pragma unroll
    for (int h = 0; h < 16; ++h) p[h] = 0.f;
    for (int it = 0; it < 16; ++it) {
        int e = l + it * 64;
        float xv = xr[e];
        #pragma unroll
        for (int h = 0; h < 16; ++h) p[h] += xv * wv2t[h * DMOD + e];
    }
    #pragma unroll
    for (int h = 0; h < 16; ++h) {
        #pragma unroll
        for (int off = 1; off < 64; off <<= 1) p[h] += __shfl_xor(p[h], off, 64);
    }
    float out = 0.f;
    #pragma unroll
    for (int h = 0; h < 16; ++h) if (l == h) out = p[h] + bv2[h];
    if (l < 16) u[(b * 16 + l) * NSEQ + j] = out;
}

// ---------------- stage 3: projection GEMM (bf16 MFMA), Q and K fused via blockIdx.z ----------------
__global__ __launch_bounds__(256) void k_gemm(
        const unsigned short* __restrict__ X,     // 2048 x 1024 bf16 row-major
        const unsigned short* __restrict__ wqt, const unsigned short* __restrict__ wkt,
        const float* __restrict__ bq, const float* __restrict__ bk,
        unsigned short* __restrict__ qT, unsigned short* __restrict__ kT) {
    const unsigned short* Wt = blockIdx.z ? wkt : wqt;
    const float* bias = blockIdx.z ? bk : bq;
    unsigned short* outT = blockIdx.z ? kT : qT;
    int w = threadIdx.x >> 6, lane = threadIdx.x & 63;
    int quad = lane >> 4, col = lane & 15;
    int m0 = blockIdx.x * 64 + w * 16;
    int n0 = blockIdx.y * 64;
    f32x4 acc[4];
    #pragma unroll
    for (int nt = 0; nt < 4; ++nt) acc[nt] = (f32x4){0.f, 0.f, 0.f, 0.f};
    const unsigned short* arow = X + (size_t)(m0 + col) * DMOD + quad * 8;
    for (int k0 = 0; k0 < DMOD; k0 += 32) {
        bf16x8 a = *(const bf16x8*)(arow + k0);
        #pragma unroll
        for (int nt = 0; nt < 4; ++nt) {
            bf16x8 bf = *(const bf16x8*)(Wt + (size_t)(n0 + nt * 16 + col) * DMOD + k0 + quad * 8);
            acc[nt] = __builtin_amdgcn_mfma_f32_16x16x32_bf16(a, bf, acc[nt], 0, 0, 0);
        }
    }
    #pragma unroll
    for (int nt = 0; nt < 4; ++nt) {
        int n = n0 + nt * 16 + col;       // D-output col
        int h = n >> 6, d = n & 63;
        float bvv = bias[n];
        #pragma unroll
        for (int r = 0; r < 4; ++r) {
            int mg = m0 + quad * 4 + r;   // D-output row
            int b = mg >> 9, i = mg & 511;
            outT[(size_t)((b * 16 + h) * NSEQ + i) * HD + d] = f2bf(acc[nt][r] + bvv);
        }
    }
}

// ---------------- stage 4: logits + bias + mask + fixed-shift exp ----------------
// Grid (32,16,4): blockIdx.x = i-tile(8) * jchunk(4). Wave: 16 i x 128 j.
// e = exp(qk/8 + bias - 30) (0 if masked) -> eW[b][i][h][j] bf16.
// spart[bh*512+i][jc] = partial sum over this j-chunk.
__global__ __launch_bounds__(256) void k_logits(
        const unsigned short* __restrict__ qT, const unsigned short* __restrict__ kT,
        const float* __restrict__ bias, const int* __restrict__ mask,
        unsigned short* __restrict__ eW, float* __restrict__ spart) {
    int w = threadIdx.x >> 6, lane = threadIdx.x & 63;
    int quad = lane >> 4, col = lane & 15;
    int b = blockIdx.z, h = blockIdx.y;
    int it = blockIdx.x >> 2, jc = blockIdx.x & 3;
    int i0 = it * 64 + w * 16;
    int bh = b * 16 + h;
    const unsigned short* qbase = qT + (size_t)(bh * NSEQ + i0 + col) * HD + quad * 8;
    bf16x8 a0 = *(const bf16x8*)(qbase);
    bf16x8 a1 = *(const bf16x8*)(qbase + 32);
    float sp[4] = {0.f, 0.f, 0.f, 0.f};
    for (int jt = 0; jt < 8; ++jt) {
        int j0 = jc * 128 + jt * 16;
        const unsigned short* kbase = kT + (size_t)(bh * NSEQ + j0 + col) * HD + quad * 8;
        bf16x8 b0 = *(const bf16x8*)(kbase);
        bf16x8 b1 = *(const bf16x8*)(kbase + 32);
        f32x4 acc = (f32x4){0.f, 0.f, 0.f, 0.f};
        acc = __builtin_amdgcn_mfma_f32_16x16x32_bf16(a0, b0, acc, 0, 0, 0);
        acc = __builtin_amdgcn_mfma_f32_16x16x32_bf16(a1, b1, acc, 0, 0, 0);
        int j = j0 + col;
        #pragma unroll
        for (int r = 0; r < 4; ++r) {
            int i = i0 + quad * 4 + r;
            float lg = acc[r] * 0.125f + bias[(size_t)(bh * NSEQ + i) * NSEQ + j];
            int mk = mask[(size_t)(b * NSEQ + i) * NSEQ + j];
            float e = (mk == 0) ? 0.f : __expf(lg - 30.f);
            sp[r] += e;
            eW[(size_t)((b * NSEQ + i) * NH + h) * NSEQ + j] = f2bf(e);
        }
    }
    #pragma unroll
    for (int r = 0; r < 4; ++r) {
        #pragma unroll
        for (int off = 1; off < 16; off <<= 1) sp[r] += __shfl_xor(sp[r], off, 64);
    }
    if (col == 0) {
        #pragma unroll
        for (int r = 0; r < 4; ++r)
            spart[(size_t)(bh * NSEQ + i0 + quad * 4 + r) * 4 + jc] = sp[r];
    }
}

// ---------------- stage 4b: sinv = 1/sum of 4 partials ----------------
__global__ void k_sinv(const float* __restrict__ spart, float* __restrict__ sinv) {
    int i = blockIdx.x * blockDim.x + threadIdx.x;   // 32768 rows
    float4 v = ((const float4*)spart)[i];
    float s = v.x + v.y + v.z + v.w;
    sinv[i] = (s > 0.f) ? 1.f / s : 0.f;
}

// ---------------- stage 5: combine: force[b,i,c] = bo + sum_j r * sum_h e*sinv*u ----------------
// eW layout [b][i][h][j]: per-(b,i) slab is 16KB contiguous -> stage in LDS.
__global__ __launch_bounds__(256) void k_combine(
        const unsigned short* __restrict__ eW, const float* __restrict__ sinv,
        const float* __restrict__ u, const float* __restrict__ r,
        const float* __restrict__ bo, float* __restrict__ out) {
    int i = blockIdx.x, b = blockIdx.y;
    int tid = threadIdx.x;
    __shared__ float su[16];
    __shared__ float red[3][4];
    __shared__ __align__(16) unsigned short elds[NH * NSEQ];   // 16 KB
    const unsigned short* esrc = eW + (size_t)(b * NSEQ + i) * NH * NSEQ;
    #pragma unroll
    for (int t = 0; t < 4; ++t)
        ((int4*)elds)[tid + t * 256] = ((const int4*)esrc)[tid + t * 256];
    if (tid < 16) su[tid] = sinv[(b * 16 + tid) * NSEQ + i];
    __syncthreads();
    int j = tid * 2;
    float s0 = 0.f, s1 = 0.f;
    #pragma unroll
    for (int h = 0; h < 16; ++h) {
        unsigned int ep = *(const unsigned int*)(elds + h * NSEQ + j);
        float wgt = su[h];
        float2 uv = *(const float2*)(u + (b * 16 + h) * NSEQ + j);
        s0 += bf2f((unsigned short)(ep & 0xffffu)) * wgt * uv.x;
        s1 += bf2f((unsigned short)(ep >> 16)) * wgt * uv.y;
    }
    float acc[3];
    #pragma unroll
    for (int c = 0; c < 3; ++c) {
        float2 rv = *(const float2*)(r + ((size_t)(b * 3 + c) * NSEQ + i) * NSEQ + j);
        acc[c] = rv.x * s0 + rv.y * s1;
    }
    #pragma unroll
    for (int c = 0; c < 3; ++c) {
        #pragma unroll
        for (int off = 1; off < 64; off <<= 1) acc[c] += __shfl_xor(acc[c], off, 64);
    }
    int w = tid >> 6, lane = tid & 63;
    if (lane == 0) { red[0][w] = acc[0]; red[1][w] = acc[1]; red[2][w] = acc[2]; }
    __syncthreads();
    if (tid == 0) {
        float bov = bo[0];
        #pragma unroll
        for (int c = 0; c < 3; ++c)
            out[(size_t)(b * NSEQ + i) * 3 + c] =
                red[c][0] + red[c][1] + red[c][2] + red[c][3] + bov;
    }
}

extern "C" void kernel_launch(void* const* d_in, const int* in_sizes, int n_in,
                              void* d_out, int out_size, void* d_ws, size_t ws_size,
                              hipStream_t stream) {
    const float* x    = (const float*)d_in[0];
    const float* rr   = (const float*)d_in[1];
    const float* bias = (const float*)d_in[2];
    const int*   mask = (const int*)d_in[3];
    const float* wq   = (const float*)d_in[4];
    const float* bq   = (const float*)d_in[5];
    const float* wk   = (const float*)d_in[6];
    const float* bk   = (const float*)d_in[7];
    const float* wv   = (const float*)d_in[8];
    const float* bv   = (const float*)d_in[9];
    const float* wo   = (const float*)d_in[10];
    const float* bo   = (const float*)d_in[11];
    float* out = (float*)d_out;

    char* ws = (char*)d_ws;
    unsigned short* xb   = (unsigned short*)(ws + 0);          //  4 MiB
    unsigned short* wqt  = (unsigned short*)(ws + 4194304);    //  2 MiB
    unsigned short* wkt  = (unsigned short*)(ws + 6291456);    //  2 MiB
    float*          wv2t = (float*)(ws + 8388608);             //  64 KiB
    float*          bv2  = (float*)(ws + 8454144);             //  256 B
    float*          u    = (float*)(ws + 8454400);             //  128 KiB
    unsigned short* qT   = (unsigned short*)(ws + 8585472);    //  4 MiB
    unsigned short* kT   = (unsigned short*)(ws + 12779776);   //  4 MiB
    unsigned short* eW   = (unsigned short*)(ws + 16974080);   //  32 MiB [b][i][h][j]
    float*          spart= (float*)(ws + 50528512);            //  512 KiB
    float*          siv  = (float*)(ws + 51052800);            //  128 KiB
    // total ~51.2 MB

    k_cvt<<<8192, 256, 0, stream>>>(x, xb, BSZ * NSEQ * DMOD);
    k_cvt_wt<<<dim3(32, 32, 2), 256, 0, stream>>>(wq, wk, wqt, wkt);
    k_wv2<<<256, 256, 0, stream>>>(wv, bv, wo, wv2t, bv2);
    k_u<<<512, 256, 0, stream>>>(x, wv2t, bv2, u);
    k_gemm<<<dim3(32, 16, 2), 256, 0, stream>>>(xb, wqt, wkt, bq, bk, qT, kT);
    k_logits<<<dim3(32, 16, 4), 256, 0, stream>>>(qT, kT, bias, mask, eW, spart);
    k_sinv<<<128, 256, 0, stream>>>(spart, siv);
    k_combine<<<dim3(512, 4), 256, 0, stream>>>(eW, siv, u, rr, bo, out);
}